// Round 46
// baseline (72.992 us; speedup 1.0000x reference)
//
#include <hip/hip_runtime.h>
#include <math.h>

#define BNS 0.99999500003749972f   // 1/sqrt(1+1e-5)

typedef float v2f __attribute__((ext_vector_type(2)));

__device__ __forceinline__ float eluf(float v) {
    return v > 0.f ? v : (__expf(v) - 1.f);
}
__device__ __forceinline__ float sigmf(float u) {
    return 1.f / (1.f + __expf(-u));
}
// force a block-uniform float into an SGPR
__device__ __forceinline__ float sgpr(float v) {
    return __int_as_float(__builtin_amdgcn_readfirstlane(__float_as_int(v)));
}

#define PSTR 1024    // pre row stride (tail [1000,1024) never read)
#define PADZ 32      // left zero pad (>= 31 = max K/2)
#define ZLEN 1120    // PADZ + 1000 + right pad

// block-wide reduce of a pair (s1,s2); 256 threads = 4 waves; 1 barrier
__device__ __forceinline__ void block_reduce2(float& s1, float& s2, float* red) {
#pragma unroll
    for (int m = 32; m > 0; m >>= 1) {
        s1 += __shfl_xor(s1, m, 64);
        s2 += __shfl_xor(s2, m, 64);
    }
    const int wid = threadIdx.x >> 6, lane = threadIdx.x & 63;
    if (lane == 0) { red[wid * 2] = s1; red[wid * 2 + 1] = s2; }
    __syncthreads();
    s1 = red[0] + red[2] + red[4] + red[6];
    s2 = red[1] + red[3] + red[5] + red[7];
}

// ---------------- kernel 1: stem conv2d(2x3,'same') + BN + ELU + spatial reduce ----------------
// grid (2 t-tiles, 3 groups, 256 batch), block 256 (250 active), 2 t per thread.
// Packed-f32 FMA chain (v_pk_fma_f32); ELU stays scalar.
__global__ __launch_bounds__(256) void k_stem(
    const float* __restrict__ x,
    const float* __restrict__ stem_w,  // (15,1,2,3)
    const float* __restrict__ stem_g, const float* __restrict__ stem_b,
    const float* __restrict__ sw1, const float* __restrict__ sw2, const float* __restrict__ sw3,
    float* __restrict__ pre)           // (256,15,PSTR)
{
    const int tid = threadIdx.x;
    const int lane = tid & 63;
    const int g = blockIdx.y;
    const int b = blockIdx.z;
    const float* xb = x + b * 22000;

    // per-lane register copy of spatial weights: lane i holds sw[c][i] (i<22)
    const float* swp = (g == 0 ? sw1 : g == 1 ? sw2 : sw3);
    float wrow[5];
#pragma unroll
    for (int c = 0; c < 5; ++c)
        wrow[c] = (lane < 22) ? swp[c * 22 + lane] : 0.f;

    if (tid >= 250) return;
    const int t0 = blockIdx.x * 500 + tid * 2;     // 0..998 even

    // block-uniform weights -> SGPRs; BN scale folded into w, bias as chain seed
    float w[5][6], bs[5];
#pragma unroll
    for (int c = 0; c < 5; ++c) {
        const int C = g * 5 + c;
        const float gsc = sgpr(stem_g[C]) * BNS;
#pragma unroll
        for (int j = 0; j < 6; ++j) w[c][j] = sgpr(stem_w[C * 6 + j]) * gsc;
        bs[c] = sgpr(stem_b[C]);
    }

    const bool sel0 = (t0 == 0), sel2 = (t0 == 998);
    const int base = sel0 ? 0 : (sel2 ? 996 : t0 - 1);

    v2f acc[5];
#pragma unroll
    for (int c = 0; c < 5; ++c) acc[c] = (v2f){0.f, 0.f};

    // window = cols t0-1 .. t0+2 (4 wide, covers both outputs); one float4/row
    #define LOADW(rp, w0, w1, w2, w3)                                   \
    {                                                                   \
        const float4 v = *reinterpret_cast<const float4*>((rp) + base); \
        w0 = sel0 ? 0.f : (sel2 ? v.y : v.x);                           \
        w1 = sel0 ? v.x : (sel2 ? v.z : v.y);                           \
        w2 = sel0 ? v.y : (sel2 ? v.w : v.z);                           \
        w3 = sel2 ? 0.f : (sel0 ? v.z : v.w);                           \
    }

    float c0, c1, c2, c3, n0, n1, n2, n3;
    LOADW(xb, c0, c1, c2, c3)
    for (int i = 0; i < 22; ++i) {
        if (i < 21) {
            LOADW(xb + (i + 1) * 1000, n0, n1, n2, n3)
        } else {
            n0 = n1 = n2 = n3 = 0.f;               // bottom H-pad row
        }
        // packed operand windows: lane0 = output t0, lane1 = output t0+1
        const v2f A  = {c0, c1};
        const v2f Bw = {c1, c2};
        const v2f Cw = {c2, c3};
        const v2f N0 = {n0, n1};
        const v2f N1 = {n1, n2};
        const v2f N2 = {n2, n3};
#pragma unroll
        for (int c = 0; c < 5; ++c) {
            const float sv = __shfl(wrow[c], i, 64);   // v_readlane: register-only
            v2f V = {bs[c], bs[c]};
            V += A  * w[c][0];
            V += Bw * w[c][1];
            V += Cw * w[c][2];
            V += N0 * w[c][3];
            V += N1 * w[c][4];
            V += N2 * w[c][5];
            const v2f E = {eluf(V.x), eluf(V.y)};
            acc[c] += E * sv;
        }
        c0 = n0; c1 = n1; c2 = n2; c3 = n3;
    }
    #undef LOADW

    float* prow0 = pre + (b * 15 + g * 5) * PSTR + t0;
#pragma unroll
    for (int c = 0; c < 5; ++c) {
        float2 o; o.x = acc[c].x; o.y = acc[c].y;
        *reinterpret_cast<float2*>(prow0 + c * PSTR) = o;
    }
}

// ---------------- kernel 2: branch, one 256-thread block per row ----------------
// Conv packed + BN/SimAM element-wise math packed as v2f (exp/rcp scalar).
template<int K>
__device__ __forceinline__ void branch_block(
    const float* __restrict__ row,
    float g1s, float b1v,
    float wreg,
    float g2s, float b2v,
    float* __restrict__ zrow,
    float* __restrict__ red,
    float* __restrict__ out40)
{
    const int tid = threadIdx.x;
    const int t0 = tid * 4;
    const bool act = tid < 250;

    if (tid < PADZ) zrow[tid] = 0.f;
    if (tid >= 32 && tid < 120) zrow[PADZ + 1000 + (tid - 32)] = 0.f;

    // ---- BN1 + ELU + sums (packed affine / sums; ELU scalar) ----
    v2f Ya = {0.f, 0.f}, Yb = {0.f, 0.f};
    float s1 = 0.f, s2 = 0.f;
    if (act) {
        const float4 v = *reinterpret_cast<const float4*>(row + t0);
        v2f Pa = {b1v, b1v}, Pb = {b1v, b1v};
        const v2f Va = {v.x, v.y}, Vb = {v.z, v.w};
        Pa += Va * g1s;
        Pb += Vb * g1s;
        Ya = (v2f){eluf(Pa.x), eluf(Pa.y)};
        Yb = (v2f){eluf(Pb.x), eluf(Pb.y)};
        const v2f S  = Ya + Yb;
        const v2f SQ = Ya * Ya + Yb * Yb;
        s1 = S.x + S.y;
        s2 = SQ.x + SQ.y;
    }
    block_reduce2(s1, s2, red);
    {
        const float mu = s1 * 1e-3f;
        const float var = s2 * 1e-3f - mu * mu;
        const float iv = 1.f / (2.f * var + 1e-12f);
        if (act) {
            const v2f MU = {mu, mu};
            const v2f CC = {1e-4f + 1e-12f, 1e-4f + 1e-12f};
            v2f Da = Ya - MU, Db = Yb - MU;
            v2f Ea = Da * Da * iv + CC;
            v2f Eb = Db * Db * iv + CC;
            const v2f Sa = {sigmf(1.f / Ea.x), sigmf(1.f / Ea.y)};
            const v2f Sb = {sigmf(1.f / Eb.x), sigmf(1.f / Eb.y)};
            const v2f Za = Sa * Ya, Zb = Sb * Yb;
            float4 z;
            z.x = Za.x; z.y = Za.y; z.z = Zb.x; z.w = Zb.y;
            *reinterpret_cast<float4*>(&zrow[PADZ + t0]) = z;
        }
    }
    __syncthreads();

    // ---- temporal depthwise conv ('same'), packed 2x v2f accumulators ----
    v2f aA = {0.f, 0.f}, aB = {0.f, 0.f};
    if (act) {
        const int A = PADZ + t0 - (K / 2) - 1;
        float W[20];
#pragma unroll
    for (int q = 0; q < 5; ++q)
            *reinterpret_cast<float4*>(&W[q * 4]) = *reinterpret_cast<const float4*>(&zrow[A + q * 4]);

#pragma unroll
        for (int cb = 0; cb < K; cb += 16) {
            float P[16];
            if (cb + 16 < K) {
#pragma unroll
                for (int q = 0; q < 4; ++q)
                    *reinterpret_cast<float4*>(&P[q * 4]) =
                        *reinterpret_cast<const float4*>(&zrow[A + cb + 20 + q * 4]);
            }
            const int DD = (K - cb < 16) ? (K - cb) : 16;
#pragma unroll
            for (int dd = 0; dd < DD; ++dd) {
                const float wv = __shfl(wreg, cb + dd, 64);
                const v2f wA = {W[dd + 1], W[dd + 2]};
                const v2f wB = {W[dd + 3], W[dd + 4]};
                aA += wA * wv;
                aB += wB * wv;
            }
            if (cb + 16 < K) {
#pragma unroll
                for (int q = 0; q < 4; ++q) W[q] = W[16 + q];
#pragma unroll
                for (int q = 0; q < 16; ++q) W[4 + q] = P[q];
            }
        }
    }

    // ---- BN2 + ELU + sums (packed) ----
    v2f Ua = {0.f, 0.f}, Ub = {0.f, 0.f};
    s1 = 0.f; s2 = 0.f;
    if (act) {
        v2f Pa = {b2v, b2v}, Pb = {b2v, b2v};
        Pa += aA * g2s;
        Pb += aB * g2s;
        Ua = (v2f){eluf(Pa.x), eluf(Pa.y)};
        Ub = (v2f){eluf(Pb.x), eluf(Pb.y)};
        const v2f S  = Ua + Ub;
        const v2f SQ = Ua * Ua + Ub * Ub;
        s1 = S.x + S.y;
        s2 = SQ.x + SQ.y;
    }
    block_reduce2(s1, s2, red);
    {
        const float mu = s1 * 1e-3f;
        const float var = s2 * 1e-3f - mu * mu;
        const float iv = 1.f / (2.f * var + 1e-12f);
        if (act) {
            const v2f MU = {mu, mu};
            const v2f CC = {1e-4f + 1e-12f, 1e-4f + 1e-12f};
            v2f Da = Ua - MU, Db = Ub - MU;
            v2f Ea = Da * Da * iv + CC;
            v2f Eb = Db * Db * iv + CC;
            const v2f Sa = {sigmf(1.f / Ea.x), sigmf(1.f / Ea.y)};
            const v2f Sb = {sigmf(1.f / Eb.x), sigmf(1.f / Eb.y)};
            const v2f Za = Sa * Ua, Zb = Sb * Ub;
            float4 z;
            z.x = Za.x; z.y = Za.y; z.z = Zb.x; z.w = Zb.y;
            *reinterpret_cast<float4*>(&zrow[PADZ + t0]) = z;
        }
    }
    __syncthreads();

    // ---- adaptive pool 1000 -> 40 ----
    if (tid < 40) {
        float s = 0.f;
#pragma unroll
        for (int q = 0; q < 25; ++q) s += zrow[PADZ + tid * 25 + q];
        out40[tid] = s * (1.f / 25.f);
    }
}

__global__ __launch_bounds__(256) void k_branch(
    const float* __restrict__ pre,
    const float* __restrict__ g1a, const float* __restrict__ b1a,
    const float* __restrict__ tw1,
    const float* __restrict__ g2a, const float* __restrict__ b2a,
    const float* __restrict__ g1b, const float* __restrict__ b1b,
    const float* __restrict__ tw2,
    const float* __restrict__ g2b, const float* __restrict__ b2b,
    const float* __restrict__ g1c, const float* __restrict__ b1c,
    const float* __restrict__ tw3,
    const float* __restrict__ g2c, const float* __restrict__ b2c,
    float* __restrict__ pooled)   // (256,15,40)
{
    __shared__ float zrow[ZLEN];
    __shared__ float red[8];

    const int row_id = blockIdx.x;               // 0..3839
    const int C = row_id % 15;
    const int br = C / 5, c = C % 5;
    const int lane = threadIdx.x & 63;

    const float* row = pre + (size_t)row_id * PSTR;
    float* out40 = pooled + row_id * 40;

    if (br == 0) {
        const float wreg = (lane < 15) ? tw1[c * 15 + lane] : 0.f;
        branch_block<15>(row, g1a[c] * BNS, b1a[c], wreg, g2a[c] * BNS, b2a[c], zrow, red, out40);
    } else if (br == 1) {
        const float wreg = (lane < 31) ? tw2[c * 31 + lane] : 0.f;
        branch_block<31>(row, g1b[c] * BNS, b1b[c], wreg, g2b[c] * BNS, b2b[c], zrow, red, out40);
    } else {
        const float wreg = (lane < 63) ? tw3[c * 63 + lane] : 0.f;
        branch_block<63>(row, g1c[c] * BNS, b1c[c], wreg, g2c[c] * BNS, b2c[c], zrow, red, out40);
    }
}

// ---------------- kernel 3: head (per batch), 128 threads ----------------
__global__ __launch_bounds__(128) void k_head(
    const float* __restrict__ pooled,   // (256,15,40)
    const float* __restrict__ pw_w, const float* __restrict__ pw_g, const float* __restrict__ pw_b,
    const float* __restrict__ d1_w, const float* __restrict__ d1_ow, const float* __restrict__ d1_ob,
    const float* __restrict__ d2_w, const float* __restrict__ d2_ow, const float* __restrict__ d2_ob,
    const float* __restrict__ fc_w, const float* __restrict__ fc_b,
    float* __restrict__ out)            // (256,4)
{
    __shared__ float P[600];
    __shared__ float A[200];
    __shared__ float Bv[200];
    __shared__ float C1[180];
    __shared__ float C2[135];
    __shared__ float D[125];
    __shared__ float mu5[5], iv5[5];

    const int b = blockIdx.x, tid = threadIdx.x;

    for (int i = tid; i < 600; i += 128) P[i] = pooled[b * 600 + i];
    __syncthreads();

    for (int i = tid; i < 200; i += 128) {
        int o = i / 40, t = i % 40;
        float s = 0.f;
        for (int cc = 0; cc < 15; ++cc) s += P[cc * 40 + t] * pw_w[o * 15 + cc];
        float v = s * (pw_g[o] * BNS) + pw_b[o];
        A[i] = eluf(v);
    }
    __syncthreads();

    if (tid < 5) {
        float s = 0.f;
        for (int t = 0; t < 40; ++t) s += A[tid * 40 + t];
        float mu = s * (1.f / 40.f);
        float v2 = 0.f;
        for (int t = 0; t < 40; ++t) { float d = A[tid * 40 + t] - mu; v2 += d * d; }
        mu5[tid] = mu;
        iv5[tid] = 1.f / (2.f * (v2 * (1.f / 40.f)) + 1e-12f);
    }
    __syncthreads();

    for (int i = tid; i < 200; i += 128) {
        int o = i / 40;
        float a = A[i];
        float d = a - mu5[o];
        float e = d * d * iv5[o] + 1e-4f;
        Bv[i] = sigmf(1.f / (e + 1e-12f)) * a;
    }
    __syncthreads();

    for (int i = tid; i < 180; i += 128) {
        int cc = i / 36, t = i % 36;
        float o = 0.f;
        for (int k = 0; k < 5; ++k) {
            float off = d1_ob[cc * 5 + k];
            for (int d = 0; d < 5; ++d) off += Bv[cc * 40 + t + d] * d1_ow[(cc * 5 + k) * 5 + d];
            float pos = (float)(t + k) + off;
            float fl = floorf(pos);
            float f = pos - fl;
            int i0 = (int)fl;
            float v0 = (i0 >= 0 && i0 < 40) ? Bv[cc * 40 + i0] : 0.f;
            float v1 = (i0 + 1 >= 0 && i0 + 1 < 40) ? Bv[cc * 40 + i0 + 1] : 0.f;
            o += (v0 * (1.f - f) + v1 * f) * d1_w[cc * 5 + k];
        }
        C1[i] = o;
    }
    __syncthreads();

    for (int i = tid; i < 135; i += 128) {
        int cc = i / 27, t = i % 27;
        float o = 0.f;
        for (int k = 0; k < 10; ++k) {
            float off = d2_ob[cc * 10 + k];
            for (int d = 0; d < 10; ++d) off += C1[cc * 36 + t + d] * d2_ow[(cc * 10 + k) * 10 + d];
            float pos = (float)(t + k) + off;
            float fl = floorf(pos);
            float f = pos - fl;
            int i0 = (int)fl;
            float v0 = (i0 >= 0 && i0 < 36) ? C1[cc * 36 + i0] : 0.f;
            float v1 = (i0 + 1 >= 0 && i0 + 1 < 36) ? C1[cc * 36 + i0 + 1] : 0.f;
            o += (v0 * (1.f - f) + v1 * f) * d2_w[cc * 10 + k];
        }
        C2[i] = o;
    }
    __syncthreads();

    for (int i = tid; i < 125; i += 128) {
        int cc = i / 25, j = i % 25;
        int s0 = (j * 27) / 25;
        int e0 = ((j + 1) * 27 + 24) / 25;
        float s = 0.f;
        for (int q = s0; q < e0; ++q) s += C2[cc * 27 + q];
        D[i] = s / (float)(e0 - s0);
    }
    __syncthreads();

    if (tid < 64) {
        float part0 = 0.f, part1 = 0.f, part2 = 0.f, part3 = 0.f;
        for (int i = tid; i < 125; i += 64) {
            const float dv = D[i];
            part0 += dv * fc_w[0 * 125 + i];
            part1 += dv * fc_w[1 * 125 + i];
            part2 += dv * fc_w[2 * 125 + i];
            part3 += dv * fc_w[3 * 125 + i];
        }
#pragma unroll
        for (int m = 32; m > 0; m >>= 1) {
            part0 += __shfl_xor(part0, m, 64);
            part1 += __shfl_xor(part1, m, 64);
            part2 += __shfl_xor(part2, m, 64);
            part3 += __shfl_xor(part3, m, 64);
        }
        if (tid == 0) {
            out[b * 4 + 0] = part0 + fc_b[0];
            out[b * 4 + 1] = part1 + fc_b[1];
            out[b * 4 + 2] = part2 + fc_b[2];
            out[b * 4 + 3] = part3 + fc_b[3];
        }
    }
}

extern "C" void kernel_launch(void* const* d_in, const int* in_sizes, int n_in,
                              void* d_out, int out_size, void* d_ws, size_t ws_size,
                              hipStream_t stream) {
    const float* x      = (const float*)d_in[0];
    const float* stem_w = (const float*)d_in[1];
    const float* stem_g = (const float*)d_in[2];
    const float* stem_b = (const float*)d_in[3];
    const float* b1_sw = (const float*)d_in[4];
    const float* b1_g1 = (const float*)d_in[5];
    const float* b1_b1 = (const float*)d_in[6];
    const float* b1_tw = (const float*)d_in[7];
    const float* b1_g2 = (const float*)d_in[8];
    const float* b1_b2 = (const float*)d_in[9];
    const float* b2_sw = (const float*)d_in[10];
    const float* b2_g1 = (const float*)d_in[11];
    const float* b2_b1 = (const float*)d_in[12];
    const float* b2_tw = (const float*)d_in[13];
    const float* b2_g2 = (const float*)d_in[14];
    const float* b2_b2 = (const float*)d_in[15];
    const float* b3_sw = (const float*)d_in[16];
    const float* b3_g1 = (const float*)d_in[17];
    const float* b3_b1 = (const float*)d_in[18];
    const float* b3_tw = (const float*)d_in[19];
    const float* b3_g2 = (const float*)d_in[20];
    const float* b3_b2 = (const float*)d_in[21];
    const float* pw_w  = (const float*)d_in[22];
    const float* pw_g  = (const float*)d_in[23];
    const float* pw_b  = (const float*)d_in[24];
    const float* d1_w  = (const float*)d_in[25];
    const float* d1_ow = (const float*)d_in[26];
    const float* d1_ob = (const float*)d_in[27];
    const float* d2_w  = (const float*)d_in[28];
    const float* d2_ow = (const float*)d_in[29];
    const float* d2_ob = (const float*)d_in[30];
    const float* fc_w  = (const float*)d_in[31];
    const float* fc_b  = (const float*)d_in[32];

    float* pre    = (float*)d_ws;                                        // 256*15*1024 f32 = 15.7 MB
    float* pooled = (float*)((char*)d_ws + (size_t)256 * 15 * PSTR * 4); // 256*15*40 f32

    k_stem<<<dim3(2, 3, 256), 256, 0, stream>>>(
        x, stem_w, stem_g, stem_b, b1_sw, b2_sw, b3_sw, pre);

    k_branch<<<3840, 256, 0, stream>>>(
        pre,
        b1_g1, b1_b1, b1_tw, b1_g2, b1_b2,
        b2_g1, b2_b1, b2_tw, b2_g2, b2_b2,
        b3_g1, b3_b1, b3_tw, b3_g2, b3_b2,
        pooled);

    k_head<<<256, 128, 0, stream>>>(
        pooled, pw_w, pw_g, pw_b,
        d1_w, d1_ow, d1_ob, d2_w, d2_ow, d2_ob,
        fc_w, fc_b, (float*)d_out);
}

// Round 47
// 72.187 us; speedup vs baseline: 1.0112x; 1.0112x over previous
//
#include <hip/hip_runtime.h>
#include <math.h>

#define BNS 0.99999500003749972f   // 1/sqrt(1+1e-5)

typedef float v2f __attribute__((ext_vector_type(2)));

__device__ __forceinline__ float eluf(float v) {
    return v > 0.f ? v : (__expf(v) - 1.f);
}
__device__ __forceinline__ float sigmf(float u) {
    return 1.f / (1.f + __expf(-u));
}
// force a block-uniform float into an SGPR
__device__ __forceinline__ float sgpr(float v) {
    return __int_as_float(__builtin_amdgcn_readfirstlane(__float_as_int(v)));
}

#define PSTR 1024    // pre row stride (tail [1000,1024) never read)
#define PADZ 32      // left zero pad (>= 31 = max K/2)
#define ZLEN 1120    // PADZ + 1000 + right pad

// block-wide reduce of a pair (s1,s2); 256 threads = 4 waves; 1 barrier
__device__ __forceinline__ void block_reduce2(float& s1, float& s2, float* red) {
#pragma unroll
    for (int m = 32; m > 0; m >>= 1) {
        s1 += __shfl_xor(s1, m, 64);
        s2 += __shfl_xor(s2, m, 64);
    }
    const int wid = threadIdx.x >> 6, lane = threadIdx.x & 63;
    if (lane == 0) { red[wid * 2] = s1; red[wid * 2 + 1] = s2; }
    __syncthreads();
    s1 = red[0] + red[2] + red[4] + red[6];
    s2 = red[1] + red[3] + red[5] + red[7];
}

// ---------------- kernel 1: stem conv2d(2x3,'same') + BN + ELU + spatial reduce ----------------
// grid (2 t-tiles, 3 groups, 256 batch), block 256 (250 active), 2 t per thread.
// Packed-f32 FMA chain (v_pk_fma_f32); ELU stays scalar.
__global__ __launch_bounds__(256) void k_stem(
    const float* __restrict__ x,
    const float* __restrict__ stem_w,  // (15,1,2,3)
    const float* __restrict__ stem_g, const float* __restrict__ stem_b,
    const float* __restrict__ sw1, const float* __restrict__ sw2, const float* __restrict__ sw3,
    float* __restrict__ pre)           // (256,15,PSTR)
{
    const int tid = threadIdx.x;
    const int lane = tid & 63;
    const int g = blockIdx.y;
    const int b = blockIdx.z;
    const float* xb = x + b * 22000;

    // per-lane register copy of spatial weights: lane i holds sw[c][i] (i<22)
    const float* swp = (g == 0 ? sw1 : g == 1 ? sw2 : sw3);
    float wrow[5];
#pragma unroll
    for (int c = 0; c < 5; ++c)
        wrow[c] = (lane < 22) ? swp[c * 22 + lane] : 0.f;

    if (tid >= 250) return;
    const int t0 = blockIdx.x * 500 + tid * 2;     // 0..998 even

    // block-uniform weights -> SGPRs; BN scale folded into w, bias as chain seed
    float w[5][6], bs[5];
#pragma unroll
    for (int c = 0; c < 5; ++c) {
        const int C = g * 5 + c;
        const float gsc = sgpr(stem_g[C]) * BNS;
#pragma unroll
        for (int j = 0; j < 6; ++j) w[c][j] = sgpr(stem_w[C * 6 + j]) * gsc;
        bs[c] = sgpr(stem_b[C]);
    }

    const bool sel0 = (t0 == 0), sel2 = (t0 == 998);
    const int base = sel0 ? 0 : (sel2 ? 996 : t0 - 1);

    v2f acc[5];
#pragma unroll
    for (int c = 0; c < 5; ++c) acc[c] = (v2f){0.f, 0.f};

    // window = cols t0-1 .. t0+2 (4 wide, covers both outputs); one float4/row
    #define LOADW(rp, w0, w1, w2, w3)                                   \
    {                                                                   \
        const float4 v = *reinterpret_cast<const float4*>((rp) + base); \
        w0 = sel0 ? 0.f : (sel2 ? v.y : v.x);                           \
        w1 = sel0 ? v.x : (sel2 ? v.z : v.y);                           \
        w2 = sel0 ? v.y : (sel2 ? v.w : v.z);                           \
        w3 = sel2 ? 0.f : (sel0 ? v.z : v.w);                           \
    }

    float c0, c1, c2, c3, n0, n1, n2, n3;
    LOADW(xb, c0, c1, c2, c3)
    for (int i = 0; i < 22; ++i) {
        if (i < 21) {
            LOADW(xb + (i + 1) * 1000, n0, n1, n2, n3)
        } else {
            n0 = n1 = n2 = n3 = 0.f;               // bottom H-pad row
        }
        // packed operand windows: lane0 = output t0, lane1 = output t0+1
        const v2f A  = {c0, c1};
        const v2f Bw = {c1, c2};
        const v2f Cw = {c2, c3};
        const v2f N0 = {n0, n1};
        const v2f N1 = {n1, n2};
        const v2f N2 = {n2, n3};
#pragma unroll
        for (int c = 0; c < 5; ++c) {
            const float sv = __shfl(wrow[c], i, 64);   // v_readlane: register-only
            v2f V = {bs[c], bs[c]};
            V += A  * w[c][0];
            V += Bw * w[c][1];
            V += Cw * w[c][2];
            V += N0 * w[c][3];
            V += N1 * w[c][4];
            V += N2 * w[c][5];
            const v2f E = {eluf(V.x), eluf(V.y)};
            acc[c] += E * sv;
        }
        c0 = n0; c1 = n1; c2 = n2; c3 = n3;
    }
    #undef LOADW

    float* prow0 = pre + (b * 15 + g * 5) * PSTR + t0;
#pragma unroll
    for (int c = 0; c < 5; ++c) {
        float2 o; o.x = acc[c].x; o.y = acc[c].y;
        *reinterpret_cast<float2*>(prow0 + c * PSTR) = o;
    }
}

// ---------------- kernel 2: branch, one 256-thread block per row ----------------
// Conv packed + BN/SimAM element-wise math packed as v2f (exp/rcp scalar).
template<int K>
__device__ __forceinline__ void branch_block(
    const float* __restrict__ row,
    float g1s, float b1v,
    float wreg,
    float g2s, float b2v,
    float* __restrict__ zrow,
    float* __restrict__ red,
    float* __restrict__ out40)
{
    const int tid = threadIdx.x;
    const int t0 = tid * 4;
    const bool act = tid < 250;

    if (tid < PADZ) zrow[tid] = 0.f;
    if (tid >= 32 && tid < 120) zrow[PADZ + 1000 + (tid - 32)] = 0.f;

    // ---- BN1 + ELU + sums (packed affine / sums; ELU scalar) ----
    v2f Ya = {0.f, 0.f}, Yb = {0.f, 0.f};
    float s1 = 0.f, s2 = 0.f;
    if (act) {
        const float4 v = *reinterpret_cast<const float4*>(row + t0);
        v2f Pa = {b1v, b1v}, Pb = {b1v, b1v};
        const v2f Va = {v.x, v.y}, Vb = {v.z, v.w};
        Pa += Va * g1s;
        Pb += Vb * g1s;
        Ya = (v2f){eluf(Pa.x), eluf(Pa.y)};
        Yb = (v2f){eluf(Pb.x), eluf(Pb.y)};
        const v2f S  = Ya + Yb;
        const v2f SQ = Ya * Ya + Yb * Yb;
        s1 = S.x + S.y;
        s2 = SQ.x + SQ.y;
    }
    block_reduce2(s1, s2, red);
    {
        const float mu = s1 * 1e-3f;
        const float var = s2 * 1e-3f - mu * mu;
        const float iv = 1.f / (2.f * var + 1e-12f);
        if (act) {
            const v2f MU = {mu, mu};
            const v2f CC = {1e-4f + 1e-12f, 1e-4f + 1e-12f};
            v2f Da = Ya - MU, Db = Yb - MU;
            v2f Ea = Da * Da * iv + CC;
            v2f Eb = Db * Db * iv + CC;
            const v2f Sa = {sigmf(1.f / Ea.x), sigmf(1.f / Ea.y)};
            const v2f Sb = {sigmf(1.f / Eb.x), sigmf(1.f / Eb.y)};
            const v2f Za = Sa * Ya, Zb = Sb * Yb;
            float4 z;
            z.x = Za.x; z.y = Za.y; z.z = Zb.x; z.w = Zb.y;
            *reinterpret_cast<float4*>(&zrow[PADZ + t0]) = z;
        }
    }
    __syncthreads();

    // ---- temporal depthwise conv ('same'), packed 2x v2f accumulators ----
    v2f aA = {0.f, 0.f}, aB = {0.f, 0.f};
    if (act) {
        const int A = PADZ + t0 - (K / 2) - 1;
        float W[20];
#pragma unroll
    for (int q = 0; q < 5; ++q)
            *reinterpret_cast<float4*>(&W[q * 4]) = *reinterpret_cast<const float4*>(&zrow[A + q * 4]);

#pragma unroll
        for (int cb = 0; cb < K; cb += 16) {
            float P[16];
            if (cb + 16 < K) {
#pragma unroll
                for (int q = 0; q < 4; ++q)
                    *reinterpret_cast<float4*>(&P[q * 4]) =
                        *reinterpret_cast<const float4*>(&zrow[A + cb + 20 + q * 4]);
            }
            const int DD = (K - cb < 16) ? (K - cb) : 16;
#pragma unroll
            for (int dd = 0; dd < DD; ++dd) {
                const float wv = __shfl(wreg, cb + dd, 64);
                const v2f wA = {W[dd + 1], W[dd + 2]};
                const v2f wB = {W[dd + 3], W[dd + 4]};
                aA += wA * wv;
                aB += wB * wv;
            }
            if (cb + 16 < K) {
#pragma unroll
                for (int q = 0; q < 4; ++q) W[q] = W[16 + q];
#pragma unroll
                for (int q = 0; q < 16; ++q) W[4 + q] = P[q];
            }
        }
    }

    // ---- BN2 + ELU + sums (packed) ----
    v2f Ua = {0.f, 0.f}, Ub = {0.f, 0.f};
    s1 = 0.f; s2 = 0.f;
    if (act) {
        v2f Pa = {b2v, b2v}, Pb = {b2v, b2v};
        Pa += aA * g2s;
        Pb += aB * g2s;
        Ua = (v2f){eluf(Pa.x), eluf(Pa.y)};
        Ub = (v2f){eluf(Pb.x), eluf(Pb.y)};
        const v2f S  = Ua + Ub;
        const v2f SQ = Ua * Ua + Ub * Ub;
        s1 = S.x + S.y;
        s2 = SQ.x + SQ.y;
    }
    block_reduce2(s1, s2, red);
    {
        const float mu = s1 * 1e-3f;
        const float var = s2 * 1e-3f - mu * mu;
        const float iv = 1.f / (2.f * var + 1e-12f);
        if (act) {
            const v2f MU = {mu, mu};
            const v2f CC = {1e-4f + 1e-12f, 1e-4f + 1e-12f};
            v2f Da = Ua - MU, Db = Ub - MU;
            v2f Ea = Da * Da * iv + CC;
            v2f Eb = Db * Db * iv + CC;
            const v2f Sa = {sigmf(1.f / Ea.x), sigmf(1.f / Ea.y)};
            const v2f Sb = {sigmf(1.f / Eb.x), sigmf(1.f / Eb.y)};
            const v2f Za = Sa * Ua, Zb = Sb * Ub;
            float4 z;
            z.x = Za.x; z.y = Za.y; z.z = Zb.x; z.w = Zb.y;
            *reinterpret_cast<float4*>(&zrow[PADZ + t0]) = z;
        }
    }
    __syncthreads();

    // ---- adaptive pool 1000 -> 40 ----
    if (tid < 40) {
        float s = 0.f;
#pragma unroll
        for (int q = 0; q < 25; ++q) s += zrow[PADZ + tid * 25 + q];
        out40[tid] = s * (1.f / 25.f);
    }
}

__global__ __launch_bounds__(256) void k_branch(
    const float* __restrict__ pre,
    const float* __restrict__ g1a, const float* __restrict__ b1a,
    const float* __restrict__ tw1,
    const float* __restrict__ g2a, const float* __restrict__ b2a,
    const float* __restrict__ g1b, const float* __restrict__ b1b,
    const float* __restrict__ tw2,
    const float* __restrict__ g2b, const float* __restrict__ b2b,
    const float* __restrict__ g1c, const float* __restrict__ b1c,
    const float* __restrict__ tw3,
    const float* __restrict__ g2c, const float* __restrict__ b2c,
    float* __restrict__ pooled)   // (256,15,40)
{
    __shared__ float zrow[ZLEN];
    __shared__ float red[8];

    const int row_id = blockIdx.x;               // 0..3839
    const int C = row_id % 15;
    const int br = C / 5, c = C % 5;
    const int lane = threadIdx.x & 63;

    const float* row = pre + (size_t)row_id * PSTR;
    float* out40 = pooled + row_id * 40;

    if (br == 0) {
        const float wreg = (lane < 15) ? tw1[c * 15 + lane] : 0.f;
        branch_block<15>(row, g1a[c] * BNS, b1a[c], wreg, g2a[c] * BNS, b2a[c], zrow, red, out40);
    } else if (br == 1) {
        const float wreg = (lane < 31) ? tw2[c * 31 + lane] : 0.f;
        branch_block<31>(row, g1b[c] * BNS, b1b[c], wreg, g2b[c] * BNS, b2b[c], zrow, red, out40);
    } else {
        const float wreg = (lane < 63) ? tw3[c * 63 + lane] : 0.f;
        branch_block<63>(row, g1c[c] * BNS, b1c[c], wreg, g2c[c] * BNS, b2c[c], zrow, red, out40);
    }
}

// ---------------- kernel 3: head (per batch), 128 threads ----------------
__global__ __launch_bounds__(128) void k_head(
    const float* __restrict__ pooled,   // (256,15,40)
    const float* __restrict__ pw_w, const float* __restrict__ pw_g, const float* __restrict__ pw_b,
    const float* __restrict__ d1_w, const float* __restrict__ d1_ow, const float* __restrict__ d1_ob,
    const float* __restrict__ d2_w, const float* __restrict__ d2_ow, const float* __restrict__ d2_ob,
    const float* __restrict__ fc_w, const float* __restrict__ fc_b,
    float* __restrict__ out)            // (256,4)
{
    __shared__ float P[600];
    __shared__ float A[200];
    __shared__ float Bv[200];
    __shared__ float C1[180];
    __shared__ float C2[135];
    __shared__ float D[125];
    __shared__ float mu5[5], iv5[5];

    const int b = blockIdx.x, tid = threadIdx.x;

    for (int i = tid; i < 600; i += 128) P[i] = pooled[b * 600 + i];
    __syncthreads();

    for (int i = tid; i < 200; i += 128) {
        int o = i / 40, t = i % 40;
        float s = 0.f;
        for (int cc = 0; cc < 15; ++cc) s += P[cc * 40 + t] * pw_w[o * 15 + cc];
        float v = s * (pw_g[o] * BNS) + pw_b[o];
        A[i] = eluf(v);
    }
    __syncthreads();

    if (tid < 5) {
        float s = 0.f;
        for (int t = 0; t < 40; ++t) s += A[tid * 40 + t];
        float mu = s * (1.f / 40.f);
        float v2 = 0.f;
        for (int t = 0; t < 40; ++t) { float d = A[tid * 40 + t] - mu; v2 += d * d; }
        mu5[tid] = mu;
        iv5[tid] = 1.f / (2.f * (v2 * (1.f / 40.f)) + 1e-12f);
    }
    __syncthreads();

    for (int i = tid; i < 200; i += 128) {
        int o = i / 40;
        float a = A[i];
        float d = a - mu5[o];
        float e = d * d * iv5[o] + 1e-4f;
        Bv[i] = sigmf(1.f / (e + 1e-12f)) * a;
    }
    __syncthreads();

    for (int i = tid; i < 180; i += 128) {
        int cc = i / 36, t = i % 36;
        float o = 0.f;
        for (int k = 0; k < 5; ++k) {
            float off = d1_ob[cc * 5 + k];
            for (int d = 0; d < 5; ++d) off += Bv[cc * 40 + t + d] * d1_ow[(cc * 5 + k) * 5 + d];
            float pos = (float)(t + k) + off;
            float fl = floorf(pos);
            float f = pos - fl;
            int i0 = (int)fl;
            float v0 = (i0 >= 0 && i0 < 40) ? Bv[cc * 40 + i0] : 0.f;
            float v1 = (i0 + 1 >= 0 && i0 + 1 < 40) ? Bv[cc * 40 + i0 + 1] : 0.f;
            o += (v0 * (1.f - f) + v1 * f) * d1_w[cc * 5 + k];
        }
        C1[i] = o;
    }
    __syncthreads();

    for (int i = tid; i < 135; i += 128) {
        int cc = i / 27, t = i % 27;
        float o = 0.f;
        for (int k = 0; k < 10; ++k) {
            float off = d2_ob[cc * 10 + k];
            for (int d = 0; d < 10; ++d) off += C1[cc * 36 + t + d] * d2_ow[(cc * 10 + k) * 10 + d];
            float pos = (float)(t + k) + off;
            float fl = floorf(pos);
            float f = pos - fl;
            int i0 = (int)fl;
            float v0 = (i0 >= 0 && i0 < 36) ? C1[cc * 36 + i0] : 0.f;
            float v1 = (i0 + 1 >= 0 && i0 + 1 < 36) ? C1[cc * 36 + i0 + 1] : 0.f;
            o += (v0 * (1.f - f) + v1 * f) * d2_w[cc * 10 + k];
        }
        C2[i] = o;
    }
    __syncthreads();

    for (int i = tid; i < 125; i += 128) {
        int cc = i / 25, j = i % 25;
        int s0 = (j * 27) / 25;
        int e0 = ((j + 1) * 27 + 24) / 25;
        float s = 0.f;
        for (int q = s0; q < e0; ++q) s += C2[cc * 27 + q];
        D[i] = s / (float)(e0 - s0);
    }
    __syncthreads();

    if (tid < 64) {
        float part0 = 0.f, part1 = 0.f, part2 = 0.f, part3 = 0.f;
        for (int i = tid; i < 125; i += 64) {
            const float dv = D[i];
            part0 += dv * fc_w[0 * 125 + i];
            part1 += dv * fc_w[1 * 125 + i];
            part2 += dv * fc_w[2 * 125 + i];
            part3 += dv * fc_w[3 * 125 + i];
        }
#pragma unroll
        for (int m = 32; m > 0; m >>= 1) {
            part0 += __shfl_xor(part0, m, 64);
            part1 += __shfl_xor(part1, m, 64);
            part2 += __shfl_xor(part2, m, 64);
            part3 += __shfl_xor(part3, m, 64);
        }
        if (tid == 0) {
            out[b * 4 + 0] = part0 + fc_b[0];
            out[b * 4 + 1] = part1 + fc_b[1];
            out[b * 4 + 2] = part2 + fc_b[2];
            out[b * 4 + 3] = part3 + fc_b[3];
        }
    }
}

extern "C" void kernel_launch(void* const* d_in, const int* in_sizes, int n_in,
                              void* d_out, int out_size, void* d_ws, size_t ws_size,
                              hipStream_t stream) {
    const float* x      = (const float*)d_in[0];
    const float* stem_w = (const float*)d_in[1];
    const float* stem_g = (const float*)d_in[2];
    const float* stem_b = (const float*)d_in[3];
    const float* b1_sw = (const float*)d_in[4];
    const float* b1_g1 = (const float*)d_in[5];
    const float* b1_b1 = (const float*)d_in[6];
    const float* b1_tw = (const float*)d_in[7];
    const float* b1_g2 = (const float*)d_in[8];
    const float* b1_b2 = (const float*)d_in[9];
    const float* b2_sw = (const float*)d_in[10];
    const float* b2_g1 = (const float*)d_in[11];
    const float* b2_b1 = (const float*)d_in[12];
    const float* b2_tw = (const float*)d_in[13];
    const float* b2_g2 = (const float*)d_in[14];
    const float* b2_b2 = (const float*)d_in[15];
    const float* b3_sw = (const float*)d_in[16];
    const float* b3_g1 = (const float*)d_in[17];
    const float* b3_b1 = (const float*)d_in[18];
    const float* b3_tw = (const float*)d_in[19];
    const float* b3_g2 = (const float*)d_in[20];
    const float* b3_b2 = (const float*)d_in[21];
    const float* pw_w  = (const float*)d_in[22];
    const float* pw_g  = (const float*)d_in[23];
    const float* pw_b  = (const float*)d_in[24];
    const float* d1_w  = (const float*)d_in[25];
    const float* d1_ow = (const float*)d_in[26];
    const float* d1_ob = (const float*)d_in[27];
    const float* d2_w  = (const float*)d_in[28];
    const float* d2_ow = (const float*)d_in[29];
    const float* d2_ob = (const float*)d_in[30];
    const float* fc_w  = (const float*)d_in[31];
    const float* fc_b  = (const float*)d_in[32];

    float* pre    = (float*)d_ws;                                        // 256*15*1024 f32 = 15.7 MB
    float* pooled = (float*)((char*)d_ws + (size_t)256 * 15 * PSTR * 4); // 256*15*40 f32

    k_stem<<<dim3(2, 3, 256), 256, 0, stream>>>(
        x, stem_w, stem_g, stem_b, b1_sw, b2_sw, b3_sw, pre);

    k_branch<<<3840, 256, 0, stream>>>(
        pre,
        b1_g1, b1_b1, b1_tw, b1_g2, b1_b2,
        b2_g1, b2_b1, b2_tw, b2_g2, b2_b2,
        b3_g1, b3_b1, b3_tw, b3_g2, b3_b2,
        pooled);

    k_head<<<256, 128, 0, stream>>>(
        pooled, pw_w, pw_g, pw_b,
        d1_w, d1_ow, d1_ob, d2_w, d2_ow, d2_ob,
        fc_w, fc_b, (float*)d_out);
}